// Round 18
// baseline (86.571 us; speedup 1.0000x reference)
//
#include <hip/hip_runtime.h>
#include <hip/hip_bf16.h>

// Interpolator == attention: out = softmax_c(z_t^T (W+W^T) z_c - q_cc[c]) @ y_context
// Msym = log2e*(W+W^T) f32; Q = z_target @ Msym (hi/lo bf16); K = z_context (hi/lo bf16)
// bias[c] = -0.5 * z_c^T Msym z_c (f32); V^T bf16 [32][8192]. No online max.
//
// R18 = R17 + amdgpu_waves_per_eu(4,4) on attn. R17's 40KB LDS made the
// compiler target 8 waves/EU -> 64-VGPR cap -> scratch spills (WRITE_SIZE
// 9->34MB, the regression). Grid only ever gives 2 blocks/CU, so pin the
// target at 4 waves/EU and let the allocator use its honest 128-VGPR budget.

typedef float f32x4 __attribute__((ext_vector_type(4)));
typedef float f32x16 __attribute__((ext_vector_type(16)));
typedef __bf16 bf16x8 __attribute__((ext_vector_type(8)));

#define LOG2E 1.4426950408889634f

static __device__ __forceinline__ unsigned short f2bf(float x) {
  unsigned u = __float_as_uint(x);
  u += 0x7fffu + ((u >> 16) & 1u);   // RNE
  return (unsigned short)(u >> 16);
}
static __device__ __forceinline__ float bf2f(unsigned short h) {
  return __uint_as_float(((unsigned)h) << 16);
}
static __device__ __forceinline__ bf16x8 ldg8(const unsigned short* p) {
  uint4 u = *reinterpret_cast<const uint4*>(p);
  return __builtin_bit_cast(bf16x8, u);
}
static __device__ __forceinline__ unsigned cvt_pk_bf16(float lo, float hi) {
  unsigned r;
  asm("v_cvt_pk_bf16_f32 %0, %1, %2" : "=v"(r) : "v"(lo), "v"(hi));
  return r;
}
// direct global->LDS DMA, 16B/lane; LDS dest = wave-uniform base + lane*16
static __device__ __forceinline__ void gl2lds(const unsigned short* g, unsigned short* l) {
  __builtin_amdgcn_global_load_lds(
      (const __attribute__((address_space(1))) unsigned int*)g,
      (__attribute__((address_space(3))) unsigned int*)l, 16, 0, 0);
}

__global__ void msym_kernel(const float* __restrict__ W, float* __restrict__ Msym) {
  int idx = blockIdx.x * 256 + threadIdx.x;   // 16 blocks -> 4096 elems
  int k = idx >> 6, d = idx & 63;
  Msym[idx] = LOG2E * (W[k * 64 + d] + W[d * 64 + k]);
}

// R8's passing prep, byte-exact: grid 6176
__global__ void prep_kernel(const float* __restrict__ zc, const float* __restrict__ yc,
                            const float* __restrict__ zt, const float* __restrict__ Msym,
                            unsigned short* __restrict__ Qh, unsigned short* __restrict__ Ql,
                            unsigned short* __restrict__ Kh, unsigned short* __restrict__ Kl,
                            unsigned short* __restrict__ Vt, float* __restrict__ bias)
{
  int b = blockIdx.x, tid = threadIdx.x;
  if (b < 2048) {                       // Q = z_t @ Msym, hi/lo split (coalesced Msym)
    int idx = b * 256 + tid;
    int t = idx >> 6, d = idx & 63;
    const float* z = zt + t * 64;
    float q = 0.f;
    #pragma unroll 8
    for (int k = 0; k < 64; ++k) q = fmaf(z[k], Msym[k * 64 + d], q);
    unsigned short h = f2bf(q);
    Qh[idx] = h;
    Ql[idx] = f2bf(q - bf2f(h));
  } else if (b < 4096) {                // K hi/lo split
    int idx = (b - 2048) * 256 + tid;
    float v = zc[idx];
    unsigned short h = f2bf(v);
    Kh[idx] = h;
    Kl[idx] = f2bf(v - bf2f(h));
  } else if (b < 6144) {                // bias[c] = -0.5 * z_c^T Msym z_c, one wave per c
    int c = (b - 4096) * 4 + (tid >> 6), j = tid & 63;
    const float* z = zc + c * 64;
    float cs = 0.f;
    #pragma unroll 8
    for (int i = 0; i < 64; ++i) cs = fmaf(z[i], Msym[i * 64 + j], cs);
    float part = cs * z[j];
    #pragma unroll
    for (int off = 32; off >= 1; off >>= 1) part += __shfl_xor(part, off, 64);
    if (j == 0) bias[c] = -0.5f * part;
  } else {                              // V transpose via LDS (alignment-safe)
    __shared__ float vt[256][33];
    int cbase = (b - 6144) * 256;       // 256 contexts per block
    #pragma unroll
    for (int k = 0; k < 32; ++k) {
      int e = k * 256 + tid;            // e = c_rel*32 + dy, coalesced read
      vt[e >> 5][e & 31] = yc[cbase * 32 + e];
    }
    __syncthreads();
    #pragma unroll
    for (int k = 0; k < 32; ++k)        // k = dy; consecutive tid -> consecutive c
      Vt[k * 8192 + cbase + tid] = f2bf(vt[tid][k]);
  }
}

// ---------------- attention kernel ----------------
// LDS supertile: 128 contexts, SINGLE-buffered (R16 STAGE verbatim).
// KhL/KlL rows = 128B (64 bf16), 8 chunks of 16B, physical chunk p holds
// logical p ^ (row&7). VL rows = 256B (128 bf16), 16 chunks, physical p holds
// logical p ^ (row&15). Staging pre-swizzles the GLOBAL source (m173).

#define STAGE(C0) { \
  const int C0_ = (C0); \
  _Pragma("unroll") \
  for (int i2 = 0; i2 < 2; ++i2) { \
    int i = wid + i2 * 8;                       /* 16 K instr-groups */ \
    int row = i * 8 + (lane >> 3); \
    int lchunk = (lane & 7) ^ (lane >> 3); \
    gl2lds(Kh + (C0_ + row) * 64 + lchunk * 8, &KhL[i * 512]); \
    gl2lds(Kl + (C0_ + row) * 64 + lchunk * 8, &KlL[i * 512]); \
  } \
  { \
    int row = wid * 4 + (lane >> 4);            /* V rows = dy 0..31 */ \
    int lchunk = (lane & 15) ^ (row & 15); \
    gl2lds(Vt + row * 8192 + C0_ + lchunk * 8, &VL[wid * 512]); \
  } }

__global__ __launch_bounds__(512)
__attribute__((amdgpu_waves_per_eu(4, 4)))
void attn_kernel(
    const unsigned short* __restrict__ Qh, const unsigned short* __restrict__ Ql,
    const unsigned short* __restrict__ Kh, const unsigned short* __restrict__ Kl,
    const unsigned short* __restrict__ Vt, const float* __restrict__ bias,
    float* __restrict__ outAcc, float* __restrict__ denA)
{
  __shared__ unsigned short KhL[128 * 64];      // 16 KB
  __shared__ unsigned short KlL[128 * 64];      // 16 KB
  __shared__ unsigned short VL[32 * 128];       // 8 KB   (total 40960 B)

  const int tid = threadIdx.x;
  const int wid = tid >> 6, lane = tid & 63;
  const int lm = lane & 31, h = lane >> 5;      // row/col-in-32, k-half
  const int tt = blockIdx.x >> 4, cq = blockIdx.x & 15;
  const int tbase = tt * 256 + wid * 32;        // this wave's 32 targets
  const int cqbase = cq * 512;                  // this block's context slice

  // Q fragments (B-operand, 32x32x16): lane holds Q[tbase+lm][kk*16 + 8h .. +7]
  bf16x8 qh[4], ql[4];
  #pragma unroll
  for (int kk = 0; kk < 4; ++kk) {
    int off = (tbase + lm) * 64 + kk * 16 + 8 * h;
    qh[kk] = ldg8(Qh + off);
    ql[kk] = ldg8(Ql + off);
  }

  f32x16 acc = (f32x16)(0.0f);                  // D: t_row=(reg&3)+8(reg>>2)+4h, dy=lm
  float den = 0.f;

  for (int st = 0; st < 4; ++st) {
    STAGE(cqbase + st * 128)
    __syncthreads();                            // stage complete (vmcnt drained)

    const int cbias = cqbase + st * 128;

    #pragma unroll
    for (int cb = 0; cb < 4; ++cb) {
      const int crow = cb * 32 + lm;            // this lane's K row (A-operand)

      // --- QK^T: S^T tile, D: c_row=(reg&3)+8(reg>>2)+4h, t=lm ---
      f32x16 sv = (f32x16)(0.0f);
      #pragma unroll
      for (int kk = 0; kk < 4; ++kk) {
        int phys = (2 * kk + h) ^ (lm & 7);
        int offr = crow * 64 + phys * 8;
        bf16x8 kh = __builtin_bit_cast(bf16x8, *reinterpret_cast<const uint4*>(&KhL[offr]));
        bf16x8 kl = __builtin_bit_cast(bf16x8, *reinterpret_cast<const uint4*>(&KlL[offr]));
        sv = __builtin_amdgcn_mfma_f32_32x32x16_bf16(kh, qh[kk], sv, 0, 0, 0);
        sv = __builtin_amdgcn_mfma_f32_32x32x16_bf16(kl, qh[kk], sv, 0, 0, 0);
        sv = __builtin_amdgcn_mfma_f32_32x32x16_bf16(kh, ql[kk], sv, 0, 0, 0);
      }

      // --- bias + exp2 + pack: uint2 j covers c = cb*32 + j*8 + 4h + 0..3 ---
      uint2 own0, own1, own2, own3;
      float psum;
      {
        f32x4 bv0 = *reinterpret_cast<const f32x4*>(bias + cbias + cb * 32 + 0 * 8 + 4 * h);
        f32x4 bv1 = *reinterpret_cast<const f32x4*>(bias + cbias + cb * 32 + 1 * 8 + 4 * h);
        f32x4 bv2 = *reinterpret_cast<const f32x4*>(bias + cbias + cb * 32 + 2 * 8 + 4 * h);
        f32x4 bv3 = *reinterpret_cast<const f32x4*>(bias + cbias + cb * 32 + 3 * 8 + 4 * h);
        float p00 = __builtin_amdgcn_exp2f(sv[0]  + bv0[0]);
        float p01 = __builtin_amdgcn_exp2f(sv[1]  + bv0[1]);
        float p02 = __builtin_amdgcn_exp2f(sv[2]  + bv0[2]);
        float p03 = __builtin_amdgcn_exp2f(sv[3]  + bv0[3]);
        float p10 = __builtin_amdgcn_exp2f(sv[4]  + bv1[0]);
        float p11 = __builtin_amdgcn_exp2f(sv[5]  + bv1[1]);
        float p12 = __builtin_amdgcn_exp2f(sv[6]  + bv1[2]);
        float p13 = __builtin_amdgcn_exp2f(sv[7]  + bv1[3]);
        float p20 = __builtin_amdgcn_exp2f(sv[8]  + bv2[0]);
        float p21 = __builtin_amdgcn_exp2f(sv[9]  + bv2[1]);
        float p22 = __builtin_amdgcn_exp2f(sv[10] + bv2[2]);
        float p23 = __builtin_amdgcn_exp2f(sv[11] + bv2[3]);
        float p30 = __builtin_amdgcn_exp2f(sv[12] + bv3[0]);
        float p31 = __builtin_amdgcn_exp2f(sv[13] + bv3[1]);
        float p32 = __builtin_amdgcn_exp2f(sv[14] + bv3[2]);
        float p33 = __builtin_amdgcn_exp2f(sv[15] + bv3[3]);
        psum = ((p00 + p01) + (p02 + p03)) + ((p10 + p11) + (p12 + p13))
             + ((p20 + p21) + (p22 + p23)) + ((p30 + p31) + (p32 + p33));
        own0.x = cvt_pk_bf16(p00, p01); own0.y = cvt_pk_bf16(p02, p03);
        own1.x = cvt_pk_bf16(p10, p11); own1.y = cvt_pk_bf16(p12, p13);
        own2.x = cvt_pk_bf16(p20, p21); own2.y = cvt_pk_bf16(p22, p23);
        own3.x = cvt_pk_bf16(p30, p31); own3.y = cvt_pk_bf16(p32, p33);
      }
      den += psum;                              // per-lane: 16 c's for t = lm

      // --- partner exchange (lane <-> lane^32): r1 = partner own[h], r2 = own[2+h]
      unsigned s1x = h ? own0.x : own1.x, s1y = h ? own0.y : own1.y;  // send own[1-h]
      unsigned s2x = h ? own2.x : own3.x, s2y = h ? own2.y : own3.y;  // send own[3-h]
      unsigned r1x = __shfl_xor((int)s1x, 32, 64);
      unsigned r1y = __shfl_xor((int)s1y, 32, 64);
      unsigned r2x = __shfl_xor((int)s2x, 32, 64);
      unsigned r2y = __shfl_xor((int)s2y, 32, 64);
      // A-frag ks'=0: h=0 -> (own0, r1) ; h=1 -> (r1, own1)   [c = 8h..8h+7]
      uint4 f0 = h ? make_uint4(r1x, r1y, own1.x, own1.y)
                   : make_uint4(own0.x, own0.y, r1x, r1y);
      // A-frag ks'=1: h=0 -> (own2, r2) ; h=1 -> (r2, own3)   [c = 16+8h..+7]
      uint4 f1 = h ? make_uint4(r2x, r2y, own3.x, own3.y)
                   : make_uint4(own2.x, own2.y, r2x, r2y);

      // --- PV: 2 k-steps of 16 contexts; V chunk = cb*4 + k2*2 + h ---
      {
        int physv0 = (cb * 4 + 0 * 2 + h) ^ (lm & 15);
        bf16x8 vf0 = __builtin_bit_cast(bf16x8, *reinterpret_cast<const uint4*>(&VL[lm * 128 + physv0 * 8]));
        bf16x8 pa0 = __builtin_bit_cast(bf16x8, f0);
        acc = __builtin_amdgcn_mfma_f32_32x32x16_bf16(pa0, vf0, acc, 0, 0, 0);
        int physv1 = (cb * 4 + 1 * 2 + h) ^ (lm & 15);
        bf16x8 vf1 = __builtin_bit_cast(bf16x8, *reinterpret_cast<const uint4*>(&VL[lm * 128 + physv1 * 8]));
        bf16x8 pa1 = __builtin_bit_cast(bf16x8, f1);
        acc = __builtin_amdgcn_mfma_f32_32x32x16_bf16(pa1, vf1, acc, 0, 0, 0);
      }
    }

    __syncthreads();   // all waves done reading before next stage overwrites
  }

  // --- epilogue: combine halves' den, accumulate slice partials ---
  den += __shfl_xor(den, 32, 64);               // both h-halves -> full c-sum
  #pragma unroll
  for (int reg = 0; reg < 16; ++reg) {
    int trow = (reg & 3) + 8 * (reg >> 2) + 4 * h;
    atomicAdd(&outAcc[(tbase + trow) * 32 + lm], acc[reg]);
  }
  if (lane < 32) atomicAdd(&denA[tbase + lane], den);
}

// out[t][dy] = num_sum / den_sum
__global__ void divide_kernel(float* __restrict__ out, const float* __restrict__ denA)
{
  int i = blockIdx.x * 256 + threadIdx.x;   // 8192*32
  out[i] = out[i] / denA[i >> 5];
}

extern "C" void kernel_launch(void* const* d_in, const int* in_sizes, int n_in,
                              void* d_out, int out_size, void* d_ws, size_t ws_size,
                              hipStream_t stream)
{
  const float* zc = (const float*)d_in[0];   // z_context (8192,64)
  const float* yc = (const float*)d_in[1];   // y_context (8192,32)
  const float* zt = (const float*)d_in[2];   // z_target  (8192,64)
  const float* W  = (const float*)d_in[3];   // W (64,64)

  unsigned short* Qh = (unsigned short*)d_ws;        // 8192*64 u16
  unsigned short* Ql = Qh + 8192 * 64;
  unsigned short* Kh = Ql + 8192 * 64;
  unsigned short* Kl = Kh + 8192 * 64;
  unsigned short* Vt = Kl + 8192 * 64;               // 32*8192 u16
  float* bias = (float*)(Vt + 32 * 8192);            // 8192 f32
  float* Msym = bias + 8192;                         // 4096 f32
  float* denA = Msym + 4096;                         // 8192 f32 (ws total ~4.83 MB)
  float* out  = (float*)d_out;

  hipMemsetAsync(out, 0, 8192 * 32 * sizeof(float), stream);
  hipMemsetAsync(denA, 0, 8192 * sizeof(float), stream);
  msym_kernel<<<16, 256, 0, stream>>>(W, Msym);
  prep_kernel<<<6176, 256, 0, stream>>>(zc, yc, zt, Msym, Qh, Ql, Kh, Kl, Vt, bias);
  attn_kernel<<<512, 512, 0, stream>>>(Qh, Ql, Kh, Kl, Vt, bias, out, denA);
  divide_kernel<<<1024, 256, 0, stream>>>(out, denA);
}

// Round 19
// 67.948 us; speedup vs baseline: 1.2741x; 1.2741x over previous
//
#include <hip/hip_runtime.h>
#include <hip/hip_bf16.h>

// Interpolator == attention: out = softmax_c(z_t^T (W+W^T) z_c - q_cc[c]) @ y_context
// Msym = log2e*(W+W^T) f32; Q = z_target @ Msym (hi/lo bf16); K = z_context (hi/lo bf16)
// bias[c] = -0.5 * z_c^T Msym z_c (f32); V^T bf16 [32][8192]. No online max.
//
// R19 = consolidation: attn reverted to R16's PROVEN body (41.7us, no spills;
// R17/R18's 32x32 path regressed via atomic-RMW traffic + suspected spills and
// two occupancy-attribute attempts failed to move VGPR). Zeroing of out/denA
// fused into msym_kernel with EXACT coverage: 1056 zero-blocks x 256 = 270336
// = 262144 (out) + 8192 (denA). Two graph nodes saved.

typedef float f32x4 __attribute__((ext_vector_type(4)));
typedef __bf16 bf16x8 __attribute__((ext_vector_type(8)));

#define LOG2E 1.4426950408889634f

static __device__ __forceinline__ unsigned short f2bf(float x) {
  unsigned u = __float_as_uint(x);
  u += 0x7fffu + ((u >> 16) & 1u);   // RNE
  return (unsigned short)(u >> 16);
}
static __device__ __forceinline__ float bf2f(unsigned short h) {
  return __uint_as_float(((unsigned)h) << 16);
}
static __device__ __forceinline__ bf16x8 ldg8(const unsigned short* p) {
  uint4 u = *reinterpret_cast<const uint4*>(p);
  return __builtin_bit_cast(bf16x8, u);
}
static __device__ __forceinline__ unsigned cvt_pk_bf16(float lo, float hi) {
  unsigned r;
  asm("v_cvt_pk_bf16_f32 %0, %1, %2" : "=v"(r) : "v"(lo), "v"(hi));
  return r;
}
// direct global->LDS DMA, 16B/lane; LDS dest = wave-uniform base + lane*16
static __device__ __forceinline__ void gl2lds(const unsigned short* g, unsigned short* l) {
  __builtin_amdgcn_global_load_lds(
      (const __attribute__((address_space(1))) unsigned int*)g,
      (__attribute__((address_space(3))) unsigned int*)l, 16, 0, 0);
}

// grid 1072: b<16 -> Msym (4096 elems); b>=16 -> zero out (262144) + denA (8192).
// Coverage: 1056 blocks x 256 = 270336 = 262144 + 8192, EXACT.
__global__ void msym_kernel(const float* __restrict__ W, float* __restrict__ Msym,
                            float* __restrict__ out, float* __restrict__ denA) {
  int b = blockIdx.x, tid = threadIdx.x;
  if (b < 16) {
    int idx = b * 256 + tid;
    int k = idx >> 6, d = idx & 63;
    Msym[idx] = LOG2E * (W[k * 64 + d] + W[d * 64 + k]);
  } else {
    int idx = (b - 16) * 256 + tid;           // [0, 270336)
    if (idx < 262144) out[idx] = 0.f;
    else denA[idx - 262144] = 0.f;
  }
}

// R8's passing prep, byte-exact: grid 6176
__global__ void prep_kernel(const float* __restrict__ zc, const float* __restrict__ yc,
                            const float* __restrict__ zt, const float* __restrict__ Msym,
                            unsigned short* __restrict__ Qh, unsigned short* __restrict__ Ql,
                            unsigned short* __restrict__ Kh, unsigned short* __restrict__ Kl,
                            unsigned short* __restrict__ Vt, float* __restrict__ bias)
{
  int b = blockIdx.x, tid = threadIdx.x;
  if (b < 2048) {                       // Q = z_t @ Msym, hi/lo split (coalesced Msym)
    int idx = b * 256 + tid;
    int t = idx >> 6, d = idx & 63;
    const float* z = zt + t * 64;
    float q = 0.f;
    #pragma unroll 8
    for (int k = 0; k < 64; ++k) q = fmaf(z[k], Msym[k * 64 + d], q);
    unsigned short h = f2bf(q);
    Qh[idx] = h;
    Ql[idx] = f2bf(q - bf2f(h));
  } else if (b < 4096) {                // K hi/lo split
    int idx = (b - 2048) * 256 + tid;
    float v = zc[idx];
    unsigned short h = f2bf(v);
    Kh[idx] = h;
    Kl[idx] = f2bf(v - bf2f(h));
  } else if (b < 6144) {                // bias[c] = -0.5 * z_c^T Msym z_c, one wave per c
    int c = (b - 4096) * 4 + (tid >> 6), j = tid & 63;
    const float* z = zc + c * 64;
    float cs = 0.f;
    #pragma unroll 8
    for (int i = 0; i < 64; ++i) cs = fmaf(z[i], Msym[i * 64 + j], cs);
    float part = cs * z[j];
    #pragma unroll
    for (int off = 32; off >= 1; off >>= 1) part += __shfl_xor(part, off, 64);
    if (j == 0) bias[c] = -0.5f * part;
  } else {                              // V transpose via LDS (alignment-safe)
    __shared__ float vt[256][33];
    int cbase = (b - 6144) * 256;       // 256 contexts per block
    #pragma unroll
    for (int k = 0; k < 32; ++k) {
      int e = k * 256 + tid;            // e = c_rel*32 + dy, coalesced read
      vt[e >> 5][e & 31] = yc[cbase * 32 + e];
    }
    __syncthreads();
    #pragma unroll
    for (int k = 0; k < 32; ++k)        // k = dy; consecutive tid -> consecutive c
      Vt[k * 8192 + cbase + tid] = f2bf(vt[tid][k]);
  }
}

// ---------------- attention kernel (R16 body, byte-exact) ----------------
// LDS supertile: 128 contexts, SINGLE-buffered. KhL/KlL rows = 128B (64 bf16),
// 8 chunks of 16B, physical chunk p holds logical p ^ (row&7). VL rows = 256B
// (128 bf16), 16 chunks, physical p holds logical p ^ (row&15). Staging
// pre-swizzles the GLOBAL source so the gl2lds LDS dest stays linear (m173).

#define STAGE(C0) { \
  const int C0_ = (C0); \
  _Pragma("unroll") \
  for (int i2 = 0; i2 < 2; ++i2) { \
    int i = wid + i2 * 8;                       /* 16 K instr-groups */ \
    int row = i * 8 + (lane >> 3); \
    int lchunk = (lane & 7) ^ (lane >> 3); \
    gl2lds(Kh + (C0_ + row) * 64 + lchunk * 8, &KhL[i * 512]); \
    gl2lds(Kl + (C0_ + row) * 64 + lchunk * 8, &KlL[i * 512]); \
  } \
  { \
    int row = wid * 4 + (lane >> 4);            /* V rows = dy 0..31 */ \
    int lchunk = (lane & 15) ^ (row & 15); \
    gl2lds(Vt + row * 8192 + C0_ + lchunk * 8, &VL[wid * 512]); \
  } }

__global__ __launch_bounds__(512, 2) void attn_kernel(
    const unsigned short* __restrict__ Qh, const unsigned short* __restrict__ Ql,
    const unsigned short* __restrict__ Kh, const unsigned short* __restrict__ Kl,
    const unsigned short* __restrict__ Vt, const float* __restrict__ bias,
    float* __restrict__ outAcc, float* __restrict__ denA)
{
  __shared__ unsigned short KhL[128 * 64];      // 16 KB
  __shared__ unsigned short KlL[128 * 64];      // 16 KB
  __shared__ unsigned short VL[32 * 128];       // 8 KB
  __shared__ __align__(16) uint2 p_lds[8][16][34];  // 34 KB; total 75776 B

  const int tid = threadIdx.x;
  const int wid = tid >> 6, lane = tid & 63;
  const int lr = lane & 15, g = lane >> 4;
  const int tt = blockIdx.x >> 3, cq = blockIdx.x & 7;
  const int tbase = tt * 128 + wid * 16;        // this wave's 16 targets
  const int cqbase = cq * 1024;                 // this block's context eighth

  // Q fragments (B-operand): lane holds Q[tbase + lr][f*32 + 8g .. +7]
  bf16x8 qh[2], ql[2];
  #pragma unroll
  for (int f = 0; f < 2; ++f) {
    int off = (tbase + lr) * 64 + f * 32 + 8 * g;
    qh[f] = ldg8(Qh + off);
    ql[f] = ldg8(Ql + off);
  }

  uint4 ones_bits = make_uint4(0x3F803F80u, 0x3F803F80u, 0x3F803F80u, 0x3F803F80u);
  bf16x8 vones = __builtin_bit_cast(bf16x8, ones_bits);

  f32x4 acc[2];                                 // [dyb]; D: t_rel=4g+r, dy=dyb*16+lr
  f32x4 den;                                    // denominator (all dy cols equal)
  acc[0] = (f32x4)(0.0f);
  acc[1] = (f32x4)(0.0f);
  den = (f32x4)(0.0f);

  for (int st = 0; st < 8; ++st) {
    STAGE(cqbase + st * 128)
    __syncthreads();                            // stage complete (vmcnt drained)

    const int cbias = cqbase + st * 128;

    // --- per-cb fused: QK^T -> +bias -> exp2 -> pack -> p_lds write (R11 body) ---
    #pragma unroll
    for (int cb = 0; cb < 8; ++cb) {
      int row = cb * 16 + lr;
      int phys0 = g ^ (row & 7);
      int phys1 = (4 + g) ^ (row & 7);
      int off0 = row * 64 + phys0 * 8;
      int off1 = row * 64 + phys1 * 8;
      bf16x8 kh0 = __builtin_bit_cast(bf16x8, *reinterpret_cast<const uint4*>(&KhL[off0]));
      bf16x8 kl0 = __builtin_bit_cast(bf16x8, *reinterpret_cast<const uint4*>(&KlL[off0]));
      bf16x8 kh1 = __builtin_bit_cast(bf16x8, *reinterpret_cast<const uint4*>(&KhL[off1]));
      bf16x8 kl1 = __builtin_bit_cast(bf16x8, *reinterpret_cast<const uint4*>(&KlL[off1]));
      f32x4 sv = (f32x4)(0.0f);
      sv = __builtin_amdgcn_mfma_f32_16x16x32_bf16(kh0, qh[0], sv, 0, 0, 0);
      sv = __builtin_amdgcn_mfma_f32_16x16x32_bf16(kl0, qh[0], sv, 0, 0, 0);
      sv = __builtin_amdgcn_mfma_f32_16x16x32_bf16(kh0, ql[0], sv, 0, 0, 0);
      sv = __builtin_amdgcn_mfma_f32_16x16x32_bf16(kh1, qh[1], sv, 0, 0, 0);
      sv = __builtin_amdgcn_mfma_f32_16x16x32_bf16(kl1, qh[1], sv, 0, 0, 0);
      sv = __builtin_amdgcn_mfma_f32_16x16x32_bf16(kh1, ql[1], sv, 0, 0, 0);
      // D-layout: element r <-> context cb*16 + 4g + r, target = tbase + lr
      f32x4 bv = *reinterpret_cast<const f32x4*>(bias + cbias + cb * 16 + 4 * g);
      float p0 = __builtin_amdgcn_exp2f(sv[0] + bv[0]);
      float p1 = __builtin_amdgcn_exp2f(sv[1] + bv[1]);
      float p2 = __builtin_amdgcn_exp2f(sv[2] + bv[2]);
      float p3 = __builtin_amdgcn_exp2f(sv[3] + bv[3]);
      uint2 w2;
      w2.x = cvt_pk_bf16(p0, p1);
      w2.y = cvt_pk_bf16(p2, p3);
      p_lds[wid][lr][cb * 4 + g] = w2;          // entry e holds contexts 4e..4e+3
    }

    // --- PV + ones-denominator over 4 k-slices of 32 contexts (R11 body) ---
    #pragma unroll
    for (int ks = 0; ks < 4; ++ks) {
      uint2 ra = p_lds[wid][lr][ks * 8 + 2 * g];        // c = ks*32+8g .. +3
      uint2 rb = p_lds[wid][lr][ks * 8 + 2 * g + 1];    // c = ks*32+8g+4 .. +7
      bf16x8 pa = __builtin_bit_cast(bf16x8, make_uint4(ra.x, ra.y, rb.x, rb.y));
      #pragma unroll
      for (int dyb = 0; dyb < 2; ++dyb) {
        int row = dyb * 16 + lr;
        int phys = (ks * 4 + g) ^ lr;           // row & 15 == lr
        bf16x8 vf = __builtin_bit_cast(bf16x8, *reinterpret_cast<const uint4*>(&VL[row * 128 + phys * 8]));
        acc[dyb] = __builtin_amdgcn_mfma_f32_16x16x32_bf16(pa, vf, acc[dyb], 0, 0, 0);
      }
      den = __builtin_amdgcn_mfma_f32_16x16x32_bf16(pa, vones, den, 0, 0, 0);
    }

    __syncthreads();   // all waves done reading before next stage overwrites
  }

  // --- accumulate eighth partials; D: t_rel = 4g+r, dy = dyb*16+lr (R11 body) ---
  #pragma unroll
  for (int dyb = 0; dyb < 2; ++dyb)
    #pragma unroll
    for (int r = 0; r < 4; ++r)
      atomicAdd(&outAcc[(tbase + 4 * g + r) * 32 + dyb * 16 + lr], acc[dyb][r]);
  if (lr == 0) {
    #pragma unroll
    for (int r = 0; r < 4; ++r)
      atomicAdd(&denA[tbase + 4 * g + r], den[r]);
  }
}

// out[t][dy] = num_sum / den_sum
__global__ void divide_kernel(float* __restrict__ out, const float* __restrict__ denA)
{
  int i = blockIdx.x * 256 + threadIdx.x;   // 8192*32
  out[i] = out[i] / denA[i >> 5];
}

extern "C" void kernel_launch(void* const* d_in, const int* in_sizes, int n_in,
                              void* d_out, int out_size, void* d_ws, size_t ws_size,
                              hipStream_t stream)
{
  const float* zc = (const float*)d_in[0];   // z_context (8192,64)
  const float* yc = (const float*)d_in[1];   // y_context (8192,32)
  const float* zt = (const float*)d_in[2];   // z_target  (8192,64)
  const float* W  = (const float*)d_in[3];   // W (64,64)

  unsigned short* Qh = (unsigned short*)d_ws;        // 8192*64 u16
  unsigned short* Ql = Qh + 8192 * 64;
  unsigned short* Kh = Ql + 8192 * 64;
  unsigned short* Kl = Kh + 8192 * 64;
  unsigned short* Vt = Kl + 8192 * 64;               // 32*8192 u16
  float* bias = (float*)(Vt + 32 * 8192);            // 8192 f32
  float* Msym = bias + 8192;                         // 4096 f32
  float* denA = Msym + 4096;                         // 8192 f32 (ws total ~4.83 MB)
  float* out  = (float*)d_out;

  msym_kernel<<<1072, 256, 0, stream>>>(W, Msym, out, denA);
  prep_kernel<<<6176, 256, 0, stream>>>(zc, yc, zt, Msym, Qh, Ql, Kh, Kl, Vt, bias);
  attn_kernel<<<512, 512, 0, stream>>>(Qh, Ql, Kh, Kl, Vt, bias, out, denA);
  divide_kernel<<<1024, 256, 0, stream>>>(out, denA);
}